// Round 2
// baseline (279.751 us; speedup 1.0000x reference)
//
#include <hip/hip_runtime.h>
#include <hip/hip_bf16.h>

typedef __attribute__((ext_vector_type(8))) short short8;
typedef __attribute__((ext_vector_type(4))) float floatx4;

#define NN     4096
#define DIN    128
#define EDIM   192
#define DMODEL 128
#define TM     128
#define LDSP   104   // 96 + 8 pad; 104*2=208 B row pitch, multiple of 16 -> aligned ds_read_b128

__device__ __forceinline__ unsigned short f2bf(float f) {
    union { float f; unsigned int i; } x; x.f = f;
    unsigned int u = x.i;
    u += 0x7FFFu + ((u >> 16) & 1u);   // RNE
    return (unsigned short)(u >> 16);
}

// Pack W (576x128 fp32, row-major) into bf16 MFMA B-fragment order:
// wf[((gs*8+ct)*64 + lane)*8 + j] = bf16(W[(gs*32 + (lane>>4)*8 + j)*128 + ct*16 + (lane&15)])
__global__ void prep_w(const float* __restrict__ W, unsigned short* __restrict__ wf) {
    const int t = blockIdx.x * 256 + threadIdx.x;      // 288*256 == 73728 exactly
    const int j    = t & 7;
    const int lane = (t >> 3) & 63;
    const int ct   = (t >> 9) & 7;
    const int s    = t >> 12;
    const int k = s * 32 + (lane >> 4) * 8 + j;
    const int n = ct * 16 + (lane & 15);
    wf[t] = f2bf(W[k * DMODEL + n]);
}

// Windowed mask max: m3[p,i] = max(mask[p,i..i+2]) with zero pad past N. Exact fp32.
__global__ void prep_m(const float* __restrict__ mask,
                       float* __restrict__ m3f, float* __restrict__ o_m) {
    const int t = blockIdx.x * 256 + threadIdx.x;      // 64*256 == 16384 exactly
    const int i = t & (NN - 1);
    float v = mask[t];
    if (i + 1 < NN) v = fmaxf(v, mask[t + 1]);
    if (i + 2 < NN) v = fmaxf(v, mask[t + 2]);
    m3f[t] = v;
    o_m[t] = v;
}

// Main fused kernel: per block, rows [i0, i0+128) of batch b, all 128 output cols.
// 4 waves; wave w owns rows [32w, 32w+32) as two 16-row MFMA tiles x 8 col-tiles.
// K = 576 staged (fp32 -> bf16) in 6 chunks of 96 into LDS.
__global__ __launch_bounds__(256) void main_k(
    const float* __restrict__ feat,
    const float* __restrict__ edgef,
    const unsigned short* __restrict__ wfrag,
    const float* __restrict__ bias,
    const float* __restrict__ m3f,
    float* __restrict__ o_res,
    float* __restrict__ o_out)
{
    __shared__ unsigned short Alds[TM * LDSP];   // 26624 B

    const int tid  = threadIdx.x;
    const int lane = tid & 63;
    const int wv   = tid >> 6;
    const int nn   = lane & 15;
    const int quad = lane >> 4;

    const int blk = blockIdx.x;
    const int b   = blk >> 5;
    const int i0  = (blk & 31) << 7;

    const float* fb = feat  + (size_t)b * NN * DIN;
    const float* eb = edgef + (size_t)b * NN * EDIM;

    floatx4 acc[2][8];
    #pragma unroll
    for (int rt = 0; rt < 2; ++rt)
        #pragma unroll
        for (int ct = 0; ct < 8; ++ct)
            acc[rt][ct] = (floatx4){0.f, 0.f, 0.f, 0.f};

    for (int ch = 0; ch < 6; ++ch) {
        __syncthreads();   // protect Alds from previous chunk's readers
        if (ch < 4) {
            // feature chunk: local k' = 3*c' + j, c' in [0,32), channels c0+c'
            const int c0 = ch << 5;
            const int q4 = tid & 7;        // group of 4 channels
            const int rb = tid >> 3;       // 0..31
            #pragma unroll
            for (int j = 0; j < 3; ++j) {
                #pragma unroll
                for (int it = 0; it < 4; ++it) {
                    const int r   = it * 32 + rb;
                    const int row = i0 + r + j;
                    float4 v = make_float4(0.f, 0.f, 0.f, 0.f);
                    if (row < NN)
                        v = *(const float4*)(fb + (size_t)row * DIN + c0 + q4 * 4);
                    const int la = r * LDSP + q4 * 12 + j;
                    Alds[la]     = f2bf(v.x);
                    Alds[la + 3] = f2bf(v.y);
                    Alds[la + 6] = f2bf(v.z);
                    Alds[la + 9] = f2bf(v.w);
                }
            }
        } else {
            // edge chunk: local k' = e - e0, contiguous
            const int e0 = (ch - 4) * 96;
            #pragma unroll
            for (int it = 0; it < 6; ++it) {
                const int q  = it * 256 + tid;   // < 1536
                const int r  = q / 12;
                const int q8 = q - r * 12;
                const float* src = eb + (size_t)(i0 + r) * EDIM + e0 + q8 * 8;
                const float4 v0 = *(const float4*)(src);
                const float4 v1 = *(const float4*)(src + 4);
                short8 s8;
                s8[0] = (short)f2bf(v0.x); s8[1] = (short)f2bf(v0.y);
                s8[2] = (short)f2bf(v0.z); s8[3] = (short)f2bf(v0.w);
                s8[4] = (short)f2bf(v1.x); s8[5] = (short)f2bf(v1.y);
                s8[6] = (short)f2bf(v1.z); s8[7] = (short)f2bf(v1.w);
                *(short8*)(&Alds[r * LDSP + q8 * 8]) = s8;
            }
        }
        __syncthreads();

        #pragma unroll
        for (int s = 0; s < 3; ++s) {
            const int gs = ch * 3 + s;
            short8 bfr[8];
            #pragma unroll
            for (int ct = 0; ct < 8; ++ct)
                bfr[ct] = ((const short8*)wfrag)[(gs * 8 + ct) * 64 + lane];
            short8 afr[2];
            #pragma unroll
            for (int rt = 0; rt < 2; ++rt)
                afr[rt] = *(const short8*)(&Alds[(wv * 32 + rt * 16 + nn) * LDSP + s * 32 + quad * 8]);
            #pragma unroll
            for (int rt = 0; rt < 2; ++rt)
                #pragma unroll
                for (int ct = 0; ct < 8; ++ct)
                    acc[rt][ct] = __builtin_amdgcn_mfma_f32_16x16x32_bf16(
                        afr[rt], bfr[ct], acc[rt][ct], 0, 0, 0);
        }
    }

    // Epilogue: bias + ReLU, jump (3-row feature mean), mask multiply, fp32 stores.
    float biasv[8];
    #pragma unroll
    for (int ct = 0; ct < 8; ++ct)
        biasv[ct] = bias[ct * 16 + nn];

    const int   p    = b & 3;
    const float inv3 = 1.0f / 3.0f;

    #pragma unroll
    for (int rt = 0; rt < 2; ++rt) {
        const int rbase = wv * 32 + rt * 16 + quad * 4;   // C/D: row = quad*4 + reg
        float mv[4];
        #pragma unroll
        for (int reg = 0; reg < 4; ++reg)
            mv[reg] = m3f[p * NN + i0 + rbase + reg];
        #pragma unroll
        for (int ct = 0; ct < 8; ++ct) {
            const int col = ct * 16 + nn;                 // C/D: col = lane&15
            float fv[6];
            #pragma unroll
            for (int t6 = 0; t6 < 6; ++t6) {
                const int row = i0 + rbase + t6;
                fv[t6] = (row < NN) ? fb[(size_t)row * DIN + col] : 0.f;
            }
            #pragma unroll
            for (int reg = 0; reg < 4; ++reg) {
                float o = acc[rt][ct][reg] + biasv[ct];
                o = fmaxf(o, 0.f);
                const float jmp = (fv[reg] + fv[reg + 1] + fv[reg + 2]) * inv3;
                const size_t off = ((size_t)b * NN + (i0 + rbase + reg)) * DMODEL + col;
                const float mm = mv[reg];
                o_out[off] = mm * o;
                o_res[off] = mm * (o + jmp);
            }
        }
    }
}

extern "C" void kernel_launch(void* const* d_in, const int* in_sizes, int n_in,
                              void* d_out, int out_size, void* d_ws, size_t ws_size,
                              hipStream_t stream) {
    const float* adj   = (const float*)d_in[0];
    const float* feat  = (const float*)d_in[1];
    const float* edgef = (const float*)d_in[2];
    const float* mask  = (const float*)d_in[3];
    const float* W     = (const float*)d_in[4];
    const float* bias  = (const float*)d_in[5];

    float* out   = (float*)d_out;
    float* o_adj = out;
    float* o_res = out + (size_t)16777216;              // 4096*4096
    float* o_out = o_res + (size_t)8388608;             // 16*4096*128
    float* o_m   = o_out + (size_t)8388608;             // + 16*4096*128 -> 4*4096 tail

    unsigned short* wfrag = (unsigned short*)d_ws;               // 73728 * 2 B
    float*          m3f   = (float*)((char*)d_ws + 73728 * 2);   // 16384 * 4 B

    // adj passthrough (output 0): pure d2d copy, fp32
    hipMemcpyAsync(o_adj, adj, (size_t)16777216 * 4, hipMemcpyDeviceToDevice, stream);

    prep_w<<<288, 256, 0, stream>>>(W, wfrag);
    prep_m<<<64, 256, 0, stream>>>(mask, m3f, o_m);
    main_k<<<512, 256, 0, stream>>>(feat, edgef, wfrag, bias, m3f, o_res, o_out);
}